// Round 1
// baseline (1579.428 us; speedup 1.0000x reference)
//
#include <hip/hip_runtime.h>

#define N_NODES 100000
#define N_EDGES 1600000
#define D 64

// -------- deg[i] = sum_{e: row[e]==i} w[e] --------
__global__ void deg_kernel(const int* __restrict__ row, const float* __restrict__ w,
                           float* __restrict__ deg) {
    int e = blockIdx.x * blockDim.x + threadIdx.x;
    if (e < N_EDGES) atomicAdd(&deg[row[e]], w[e]);
}

// -------- dinv[i] = deg>0 ? rsqrt(deg) : 0 --------
__global__ void dinv_kernel(const float* __restrict__ deg, float* __restrict__ dinv) {
    int i = blockIdx.x * blockDim.x + threadIdx.x;
    if (i < N_NODES) {
        float d = deg[i];
        dinv[i] = d > 0.0f ? rsqrtf(d) : 0.0f;
    }
}

// -------- Tx1[col] += norm * x[row], norm = -dinv[row]*w*dinv[col] --------
// 16 threads per edge, each handling a float4 chunk of the 64-dim feature.
__global__ void scatter_kernel(const int* __restrict__ row, const int* __restrict__ col,
                               const float* __restrict__ w, const float* __restrict__ dinv,
                               const float* __restrict__ x, float* __restrict__ tx1) {
    int t = blockIdx.x * blockDim.x + threadIdx.x;
    int e = t >> 4;
    if (e >= N_EDGES) return;
    int c4 = (t & 15) << 2;
    int r  = row[e];
    int c  = col[e];
    float coeff = -dinv[r] * w[e] * dinv[c];
    const float4 xv = *(const float4*)(x + (size_t)r * D + c4);
    float* dst = tx1 + (size_t)c * D + c4;
    atomicAdd(dst + 0, coeff * xv.x);
    atomicAdd(dst + 1, coeff * xv.y);
    atomicAdd(dst + 2, coeff * xv.z);
    atomicAdd(dst + 3, coeff * xv.w);
}

// -------- out = x @ W0 + Tx1 @ W1 + b --------
// Block: 256 threads = 16 nodes x 16 j-groups; each thread computes 4 output
// features. W0/W1 staged in LDS (32 KB), node rows staged in LDS.
__global__ __launch_bounds__(256) void out_kernel(const float* __restrict__ x,
                                                  const float* __restrict__ tx1,
                                                  const float* __restrict__ W0,
                                                  const float* __restrict__ W1,
                                                  const float* __restrict__ b,
                                                  float* __restrict__ out) {
    __shared__ float W0s[D * D];
    __shared__ float W1s[D * D];
    __shared__ float xs[16][D];
    __shared__ float ts[16][D];
    int tid = threadIdx.x;

    // Load weights: 4096 floats each; 256 threads x float4 x 4 iters.
    for (int i = tid * 4; i < D * D; i += 256 * 4) {
        *(float4*)(W0s + i) = *(const float4*)(W0 + i);
        *(float4*)(W1s + i) = *(const float4*)(W1 + i);
    }
    int node0 = blockIdx.x * 16;
    {
        // 16 rows x 64 floats = 256 float4 loads, one per thread.
        int n = tid >> 4;
        int f = (tid & 15) << 2;
        const float* xp = x   + (size_t)(node0 + n) * D + f;
        const float* tp = tx1 + (size_t)(node0 + n) * D + f;
        *(float4*)(&xs[n][f]) = *(const float4*)xp;
        *(float4*)(&ts[n][f]) = *(const float4*)tp;
    }
    __syncthreads();

    int n = tid >> 4;
    int j = (tid & 15) << 2;
    float4 acc = *(const float4*)(b + j);
    #pragma unroll
    for (int k = 0; k < D; ++k) {
        float a = xs[n][k];
        float t = ts[n][k];
        float4 w0 = *(const float4*)(W0s + k * D + j);
        float4 w1 = *(const float4*)(W1s + k * D + j);
        acc.x += a * w0.x + t * w1.x;
        acc.y += a * w0.y + t * w1.y;
        acc.z += a * w0.z + t * w1.z;
        acc.w += a * w0.w + t * w1.w;
    }
    *(float4*)(out + (size_t)(node0 + n) * D + j) = acc;
}

extern "C" void kernel_launch(void* const* d_in, const int* in_sizes, int n_in,
                              void* d_out, int out_size, void* d_ws, size_t ws_size,
                              hipStream_t stream) {
    const float* x    = (const float*)d_in[0];
    const int*   eidx = (const int*)d_in[1];   // [2, E] row-major: row then col
    const float* ew   = (const float*)d_in[2];
    const float* W0   = (const float*)d_in[3];
    const float* W1   = (const float*)d_in[4];
    const float* b    = (const float*)d_in[5];
    float* out = (float*)d_out;

    const int* row = eidx;
    const int* col = eidx + N_EDGES;

    // Workspace layout
    float* tx1  = (float*)d_ws;                                   // N*D floats
    float* deg  = (float*)((char*)d_ws + (size_t)N_NODES * D * 4); // N floats
    float* dinv = deg + N_NODES;                                   // N floats

    // Zero tx1 + deg (ws is poisoned 0xAA before every call).
    hipMemsetAsync(d_ws, 0, (size_t)N_NODES * D * 4 + (size_t)N_NODES * 4, stream);

    deg_kernel<<<(N_EDGES + 255) / 256, 256, 0, stream>>>(row, ew, deg);
    dinv_kernel<<<(N_NODES + 255) / 256, 256, 0, stream>>>(deg, dinv);

    long long scatter_threads = (long long)N_EDGES * 16;
    scatter_kernel<<<(int)((scatter_threads + 255) / 256), 256, 0, stream>>>(
        row, col, ew, dinv, x, tx1);

    out_kernel<<<N_NODES / 16, 256, 0, stream>>>(x, tx1, W0, W1, b, out);
}

// Round 2
// 431.082 us; speedup vs baseline: 3.6639x; 3.6639x over previous
//
#include <hip/hip_runtime.h>

#define N_NODES 100000
#define N_EDGES 1600000
#define D 64

#define SCAN_ELEMS 1024
#define SCAN_NBLOCKS 98   // ceil(100000/1024)

// -------- fused histogram: deg[row] += w  and  counts[col] += 1 --------
__global__ void hist_kernel(const int* __restrict__ row, const int* __restrict__ col,
                            const float* __restrict__ w,
                            float* __restrict__ deg, int* __restrict__ counts) {
    int e = blockIdx.x * blockDim.x + threadIdx.x;
    if (e < N_EDGES) {
        atomicAdd(&deg[row[e]], w[e]);
        atomicAdd(&counts[col[e]], 1);
    }
}

// -------- dinv[i] = deg>0 ? rsqrt(deg) : 0 --------
__global__ void dinv_kernel(const float* __restrict__ deg, float* __restrict__ dinv) {
    int i = blockIdx.x * blockDim.x + threadIdx.x;
    if (i < N_NODES) {
        float d = deg[i];
        dinv[i] = d > 0.0f ? rsqrtf(d) : 0.0f;
    }
}

// -------- scan phase 1: per-block sums of counts (1024 elems/block) --------
__global__ __launch_bounds__(256) void scan_sums(const int* __restrict__ counts,
                                                 int* __restrict__ blockSums) {
    __shared__ int lds[256];
    int t = threadIdx.x;
    int base = blockIdx.x * SCAN_ELEMS + t * 4;
    int s = 0;
    #pragma unroll
    for (int i = 0; i < 4; ++i) {
        int idx = base + i;
        if (idx < N_NODES) s += counts[idx];
    }
    lds[t] = s;
    __syncthreads();
    for (int off = 128; off > 0; off >>= 1) {
        if (t < off) lds[t] += lds[t + off];
        __syncthreads();
    }
    if (t == 0) blockSums[blockIdx.x] = lds[0];
}

// -------- scan phase 2: exclusive scan of 98 block sums (single block) ----
__global__ __launch_bounds__(128) void scan_offsets(int* __restrict__ blockSums) {
    __shared__ int lds[128];
    int t = threadIdx.x;
    int v = (t < SCAN_NBLOCKS) ? blockSums[t] : 0;
    lds[t] = v;
    __syncthreads();
    for (int off = 1; off < 128; off <<= 1) {
        int u = (t >= off) ? lds[t - off] : 0;
        __syncthreads();
        lds[t] += u;
        __syncthreads();
    }
    if (t < SCAN_NBLOCKS) blockSums[t] = (t > 0) ? lds[t - 1] : 0;
}

// -------- scan phase 3: emit exclusive starts[] --------
__global__ __launch_bounds__(256) void scan_emit(const int* __restrict__ counts,
                                                 const int* __restrict__ blockSums,
                                                 int* __restrict__ starts) {
    __shared__ int lds[256];
    int t = threadIdx.x;
    int base = blockIdx.x * SCAN_ELEMS + t * 4;
    int c[4];
    int s = 0;
    #pragma unroll
    for (int i = 0; i < 4; ++i) {
        int idx = base + i;
        c[i] = (idx < N_NODES) ? counts[idx] : 0;
        s += c[i];
    }
    lds[t] = s;
    __syncthreads();
    for (int off = 1; off < 256; off <<= 1) {
        int u = (t >= off) ? lds[t - off] : 0;
        __syncthreads();
        lds[t] += u;
        __syncthreads();
    }
    int excl = ((t > 0) ? lds[t - 1] : 0) + blockSums[blockIdx.x];
    #pragma unroll
    for (int i = 0; i < 4; ++i) {
        int idx = base + i;
        if (idx < N_NODES) starts[idx] = excl;
        excl += c[i];
    }
}

// -------- bucket: counting-sort edges by col into (row, coeff) records ----
__global__ void bucket_kernel(const int* __restrict__ row, const int* __restrict__ col,
                              const float* __restrict__ w, const float* __restrict__ dinv,
                              const int* __restrict__ starts, int* __restrict__ cursor,
                              float2* __restrict__ recs) {
    int e = blockIdx.x * blockDim.x + threadIdx.x;
    if (e >= N_EDGES) return;
    int r = row[e];
    int c = col[e];
    float coeff = -dinv[r] * w[e] * dinv[c];
    int pos = starts[c] + atomicAdd(&cursor[c], 1);
    recs[pos] = make_float2(__int_as_float(r), coeff);
}

// -------- gather: Tx1[n] = sum over node n's edges, no atomics --------
// 16 threads per node, each owns a float4 chunk of the 64-dim row.
__global__ __launch_bounds__(256) void gather_kernel(const float2* __restrict__ recs,
                                                     const int* __restrict__ starts,
                                                     const int* __restrict__ counts,
                                                     const float* __restrict__ x,
                                                     float* __restrict__ tx1) {
    int tid = threadIdx.x;
    int g = tid >> 4;
    int lane4 = (tid & 15) << 2;
    int n = blockIdx.x * 16 + g;
    int s = starts[n];
    int cnt = counts[n];
    float4 acc = make_float4(0.f, 0.f, 0.f, 0.f);
    for (int k = 0; k < cnt; ++k) {
        float2 rec = recs[s + k];
        int r = __float_as_int(rec.x);
        float cf = rec.y;
        const float4 xv = *(const float4*)(x + (size_t)r * D + lane4);
        acc.x += cf * xv.x;
        acc.y += cf * xv.y;
        acc.z += cf * xv.z;
        acc.w += cf * xv.w;
    }
    *(float4*)(tx1 + (size_t)n * D + lane4) = acc;
}

// -------- out = x @ W0 + Tx1 @ W1 + b --------
__global__ __launch_bounds__(256) void out_kernel(const float* __restrict__ x,
                                                  const float* __restrict__ tx1,
                                                  const float* __restrict__ W0,
                                                  const float* __restrict__ W1,
                                                  const float* __restrict__ b,
                                                  float* __restrict__ out) {
    __shared__ float W0s[D * D];
    __shared__ float W1s[D * D];
    __shared__ float xs[16][D];
    __shared__ float ts[16][D];
    int tid = threadIdx.x;

    for (int i = tid * 4; i < D * D; i += 256 * 4) {
        *(float4*)(W0s + i) = *(const float4*)(W0 + i);
        *(float4*)(W1s + i) = *(const float4*)(W1 + i);
    }
    int node0 = blockIdx.x * 16;
    {
        int n = tid >> 4;
        int f = (tid & 15) << 2;
        const float* xp = x   + (size_t)(node0 + n) * D + f;
        const float* tp = tx1 + (size_t)(node0 + n) * D + f;
        *(float4*)(&xs[n][f]) = *(const float4*)xp;
        *(float4*)(&ts[n][f]) = *(const float4*)tp;
    }
    __syncthreads();

    int n = tid >> 4;
    int j = (tid & 15) << 2;
    float4 acc = *(const float4*)(b + j);
    #pragma unroll
    for (int k = 0; k < D; ++k) {
        float a = xs[n][k];
        float t = ts[n][k];
        float4 w0 = *(const float4*)(W0s + k * D + j);
        float4 w1 = *(const float4*)(W1s + k * D + j);
        acc.x += a * w0.x + t * w1.x;
        acc.y += a * w0.y + t * w1.y;
        acc.z += a * w0.z + t * w1.z;
        acc.w += a * w0.w + t * w1.w;
    }
    *(float4*)(out + (size_t)(node0 + n) * D + j) = acc;
}

extern "C" void kernel_launch(void* const* d_in, const int* in_sizes, int n_in,
                              void* d_out, int out_size, void* d_ws, size_t ws_size,
                              hipStream_t stream) {
    const float* x    = (const float*)d_in[0];
    const int*   eidx = (const int*)d_in[1];   // [2, E]: row then col
    const float* ew   = (const float*)d_in[2];
    const float* W0   = (const float*)d_in[3];
    const float* W1   = (const float*)d_in[4];
    const float* b    = (const float*)d_in[5];
    float* out = (float*)d_out;

    const int* row = eidx;
    const int* col = eidx + N_EDGES;

    // Workspace layout (all 4-byte elems)
    float* tx1       = (float*)d_ws;                        // N*D
    float* deg       = tx1 + (size_t)N_NODES * D;           // N
    float* dinv      = deg + N_NODES;                       // N
    int*   counts    = (int*)(dinv + N_NODES);              // N
    int*   starts    = counts + N_NODES;                    // N
    int*   cursor    = starts + N_NODES;                    // N
    int*   blockSums = cursor + N_NODES;                    // 128
    float2* recs     = (float2*)(blockSums + 128);          // E   (8B-aligned: 6,900,128 elems * 4B)

    // Zero deg..cursor (5N ints = 2 MB). tx1/starts/dinv fully overwritten.
    hipMemsetAsync(deg, 0, (size_t)5 * N_NODES * 4, stream);

    hist_kernel<<<(N_EDGES + 255) / 256, 256, 0, stream>>>(row, col, ew, deg, counts);
    dinv_kernel<<<(N_NODES + 255) / 256, 256, 0, stream>>>(deg, dinv);

    scan_sums   <<<SCAN_NBLOCKS, 256, 0, stream>>>(counts, blockSums);
    scan_offsets<<<1, 128, 0, stream>>>(blockSums);
    scan_emit   <<<SCAN_NBLOCKS, 256, 0, stream>>>(counts, blockSums, starts);

    bucket_kernel<<<(N_EDGES + 255) / 256, 256, 0, stream>>>(
        row, col, ew, dinv, starts, cursor, recs);

    gather_kernel<<<N_NODES / 16, 256, 0, stream>>>(recs, starts, counts, x, tx1);

    out_kernel<<<N_NODES / 16, 256, 0, stream>>>(x, tx1, W0, W1, b, out);
}